// Round 1
// baseline (68931.549 us; speedup 1.0000x reference)
//
#include <hip/hip_runtime.h>

#define B_ 4
#define D_ 128
#define H_ 128
#define W_ 32
#define CI 32
#define CO 64
#define OD 64
#define OH 64
#define OW 32
#define S_SPATIAL (OD*OH*OW)   // 131072
#define EPS 1e-5f
#define ALPHA 0.2f

__global__ __launch_bounds__(512) void zero_ws_kernel(float* ws) {
    ws[threadIdx.x] = 0.f;   // 512 floats: sums + sumsqs
}

// Direct conv: block = (b, od, oh); thread t: co = t&63, ow group = (t>>6)*8 .. +7
__global__ __launch_bounds__(256) void conv_kernel(const float* __restrict__ x,
                                                   const float* __restrict__ w,
                                                   float* __restrict__ out) {
    int bid = blockIdx.x;
    int b  = bid >> 12;       // / (64*64)
    int r  = bid & 4095;
    int od = r >> 6;
    int oh = r & 63;
    int t  = threadIdx.x;
    int co = t & 63;
    int owq = t >> 6;         // 0..3

    const float* xb = x + (size_t)b * (D_*H_*W_*CI);
    const float* wb = w + (size_t)b * (27*CI*CO);

    float acc[8];
#pragma unroll
    for (int j = 0; j < 8; ++j) acc[j] = 0.f;

    for (int kd = 0; kd < 3; ++kd) {
        int id = od*2 + kd;
        if (id >= D_) break;
        for (int kh = 0; kh < 3; ++kh) {
            int ih = oh*2 + kh;
            if (ih >= H_) break;
            const float* xrow = xb + (size_t)(id*H_ + ih) * (W_*CI);
            for (int kw = 0; kw < 3; ++kw) {
                const float* wk = wb + ((kd*3 + kh)*3 + kw)*CI*CO;
                int iwbase = owq*8 + kw - 1;
#pragma unroll
                for (int ci4 = 0; ci4 < 8; ++ci4) {
                    float4 xv[8];
#pragma unroll
                    for (int j = 0; j < 8; ++j) {
                        int iw = iwbase + j;
                        if (iw >= 0 && iw < W_)
                            xv[j] = *(const float4*)(xrow + iw*CI + ci4*4);
                        else
                            xv[j] = make_float4(0.f, 0.f, 0.f, 0.f);
                    }
                    float wv0 = wk[(ci4*4 + 0)*CO + co];
                    float wv1 = wk[(ci4*4 + 1)*CO + co];
                    float wv2 = wk[(ci4*4 + 2)*CO + co];
                    float wv3 = wk[(ci4*4 + 3)*CO + co];
#pragma unroll
                    for (int j = 0; j < 8; ++j) {
                        acc[j] = fmaf(xv[j].x, wv0, acc[j]);
                        acc[j] = fmaf(xv[j].y, wv1, acc[j]);
                        acc[j] = fmaf(xv[j].z, wv2, acc[j]);
                        acc[j] = fmaf(xv[j].w, wv3, acc[j]);
                    }
                }
            }
        }
    }

    float* orow = out + (size_t)((b*OD + od)*OH + oh) * (OW*CO);
#pragma unroll
    for (int j = 0; j < 8; ++j) {
        int ow = owq*8 + j;
        orow[ow*CO + co] = acc[j];
    }
}

// Per-(b,co) sum and sumsq over spatial. grid = 4*256 blocks.
__global__ __launch_bounds__(256) void stats_kernel(const float* __restrict__ y,
                                                    float* __restrict__ ws) {
    int b   = blockIdx.x >> 8;
    int blk = blockIdx.x & 255;
    int t   = threadIdx.x;
    int co  = t & 63;
    int pq  = t >> 6;
    const float* yb = y + (size_t)b * S_SPATIAL * CO;
    float sum = 0.f, sq = 0.f;
    for (int p = blk*4 + pq; p < S_SPATIAL; p += 1024) {
        float v = yb[(size_t)p*CO + co];
        sum += v;
        sq = fmaf(v, v, sq);
    }
    __shared__ float ssum[256];
    __shared__ float ssq[256];
    ssum[t] = sum; ssq[t] = sq;
    __syncthreads();
    if (t < 64) {
        float s = ssum[t] + ssum[t+64] + ssum[t+128] + ssum[t+192];
        float q = ssq[t]  + ssq[t+64]  + ssq[t+128]  + ssq[t+192];
        atomicAdd(&ws[b*64 + t], s);
        atomicAdd(&ws[256 + b*64 + t], q);
    }
}

// ws[0..255]=sum, ws[256..511]=sumsq  ->  ws[512..767]=scale, ws[768..1023]=shift
__global__ __launch_bounds__(256) void finalize_kernel(float* ws,
                                                       const float* __restrict__ gamma,
                                                       const float* __restrict__ beta) {
    int t = threadIdx.x;       // t = b*64 + co
    int co = t & 63;
    const float invS = 1.0f / (float)S_SPATIAL;
    float sum = ws[t];
    float sq  = ws[256 + t];
    float mu  = sum * invS;
    float var = sq * invS - mu*mu;
    float scale = rsqrtf(var + EPS) * gamma[co];
    ws[512 + t] = scale;
    ws[768 + t] = beta[co] - mu*scale;
}

// In-place normalize + leaky relu, float4 per thread.
__global__ __launch_bounds__(256) void norm_kernel(float* __restrict__ y,
                                                   const float* __restrict__ ws) {
    size_t i = (size_t)blockIdx.x * 256 + threadIdx.x;  // float4 index, total 8388608
    int b = (int)(i >> 21);                              // 2097152 float4 per sample
    const float4* scp = (const float4*)(ws + 512 + b*64);
    const float4* shp = (const float4*)(ws + 768 + b*64);
    float4 sc = scp[i & 15];
    float4 sh = shp[i & 15];
    float4 v = ((const float4*)y)[i];
    float4 r;
    r.x = fmaf(v.x, sc.x, sh.x);
    r.y = fmaf(v.y, sc.y, sh.y);
    r.z = fmaf(v.z, sc.z, sh.z);
    r.w = fmaf(v.w, sc.w, sh.w);
    r.x = r.x >= 0.f ? r.x : ALPHA * r.x;
    r.y = r.y >= 0.f ? r.y : ALPHA * r.y;
    r.z = r.z >= 0.f ? r.z : ALPHA * r.z;
    r.w = r.w >= 0.f ? r.w : ALPHA * r.w;
    ((float4*)y)[i] = r;
}

extern "C" void kernel_launch(void* const* d_in, const int* in_sizes, int n_in,
                              void* d_out, int out_size, void* d_ws, size_t ws_size,
                              hipStream_t stream) {
    const float* x     = (const float*)d_in[0];
    const float* w     = (const float*)d_in[1];
    const float* gamma = (const float*)d_in[2];
    const float* beta  = (const float*)d_in[3];
    float* out = (float*)d_out;
    float* ws  = (float*)d_ws;

    zero_ws_kernel<<<1, 512, 0, stream>>>(ws);
    conv_kernel<<<B_*OD*OH, 256, 0, stream>>>(x, w, out);
    stats_kernel<<<B_*256, 256, 0, stream>>>(out, ws);
    finalize_kernel<<<1, 256, 0, stream>>>(ws, gamma, beta);
    norm_kernel<<<32768, 256, 0, stream>>>(out, ws);
}

// Round 2
// 364.393 us; speedup vs baseline: 189.1684x; 189.1684x over previous
//
#include <hip/hip_runtime.h>

#define B_ 4
#define D_ 128
#define H_ 128
#define W_ 32
#define CI 32
#define CO 64
#define OD 64
#define OH 64
#define OW 32
#define S_SPATIAL (OD*OH*OW)   // 131072
#define EPS 1e-5f
#define ALPHA 0.2f

typedef __attribute__((ext_vector_type(8))) short short8;
typedef __attribute__((ext_vector_type(4))) float f32x4;

__device__ inline short f2bf(float f) {
    // RNE float->bf16 (inputs finite); compiler may fuse pairs into v_cvt_pk_bf16_f32
    union { float f; unsigned u; } v; v.f = f;
    unsigned r = v.u + 0x7FFFu + ((v.u >> 16) & 1u);
    return (short)(r >> 16);
}

__global__ __launch_bounds__(512) void zero_ws_kernel(float* ws) {
    ws[threadIdx.x] = 0.f;   // 512 floats: sums + sumsqs
}

// Repack w[b,kd,kh,kw,ci,co] f32 -> bf16 lane-ordered B-fragments.
// Block = (b,tap,nf); lane l supplies B[k=(l>>4)*8+j][n=nf*16+(l&15)], stored contiguous.
__global__ __launch_bounds__(64) void wprep_kernel(const float* __restrict__ w,
                                                   short* __restrict__ wp) {
    int blk = blockIdx.x;          // ((b*27+tap)*4+nf)
    int nf  = blk & 3;
    int tb  = blk >> 2;            // b*27+tap
    int l   = threadIdx.x;
    int l15 = l & 15, lhi = l >> 4;
    const float* wsrc = w + (size_t)tb * (CI*CO);   // [ci][co]
    short8 v;
#pragma unroll
    for (int j = 0; j < 8; ++j)
        v[j] = f2bf(wsrc[(lhi*8 + j)*CO + nf*16 + l15]);
    *(short8*)(wp + (size_t)blk*512 + l*8) = v;
}

// Implicit-GEMM conv via MFMA. Block = (b, od, oh-quad). Wave wv owns oh row oh0+wv,
// M=32 (two 16-row frags over ow), N=64 (four 16-col frags). K-loop = 27 taps.
__global__ __launch_bounds__(256) void conv_mfma_kernel(const float* __restrict__ x,
                                                        const short* __restrict__ wp,
                                                        float* __restrict__ out) {
    const int bid = blockIdx.x;
    const int b   = bid >> 10;
    const int od  = (bid >> 4) & 63;
    const int oh0 = (bid & 15) << 2;
    const int t   = threadIdx.x;
    const int wv  = t >> 6;
    const int l   = t & 63;
    const int l15 = l & 15;
    const int lhi = l >> 4;        // 0..3
    const int ci0 = lhi * 8;

    const int oh = oh0 + wv;
    const float* xb  = x + (size_t)b * (D_*H_*W_*CI);
    const short* wpb = wp + (size_t)b * (27*2048);

    f32x4 acc[2][4];
#pragma unroll
    for (int mf = 0; mf < 2; ++mf)
#pragma unroll
        for (int nf = 0; nf < 4; ++nf)
            acc[mf][nf] = (f32x4){0.f, 0.f, 0.f, 0.f};

    for (int kd = 0; kd < 3; ++kd) {
        int id = od*2 + kd;
        if (id >= D_) break;                   // block-uniform
        for (int kh = 0; kh < 3; ++kh) {
            int ih = oh*2 + kh;
            if (ih >= H_) continue;            // wave-uniform
            const float* xrow = xb + (size_t)(id*H_ + ih) * (W_*CI);
            const short* wrow = wpb + (size_t)((kd*3 + kh)*3) * 2048;
#pragma unroll
            for (int kw = 0; kw < 3; ++kw) {
                const short* wpt = wrow + kw*2048;
                short8 bfrag[4];
#pragma unroll
                for (int nf = 0; nf < 4; ++nf)
                    bfrag[nf] = *(const short8*)(wpt + nf*512 + l*8);

                short8 afrag[2];
#pragma unroll
                for (int mf = 0; mf < 2; ++mf) {
                    int iw = mf*16 + l15 + kw - 1;
                    float4 v0, v1;
                    if ((unsigned)iw < (unsigned)W_) {
                        v0 = *(const float4*)(xrow + iw*CI + ci0);
                        v1 = *(const float4*)(xrow + iw*CI + ci0 + 4);
                    } else {
                        v0 = make_float4(0.f,0.f,0.f,0.f);
                        v1 = v0;
                    }
                    short8 af;
                    af[0] = f2bf(v0.x); af[1] = f2bf(v0.y);
                    af[2] = f2bf(v0.z); af[3] = f2bf(v0.w);
                    af[4] = f2bf(v1.x); af[5] = f2bf(v1.y);
                    af[6] = f2bf(v1.z); af[7] = f2bf(v1.w);
                    afrag[mf] = af;
                }
#pragma unroll
                for (int mf = 0; mf < 2; ++mf)
#pragma unroll
                    for (int nf = 0; nf < 4; ++nf)
                        acc[mf][nf] = __builtin_amdgcn_mfma_f32_16x16x32_bf16(
                            afrag[mf], bfrag[nf], acc[mf][nf], 0, 0, 0);
            }
        }
    }

    // C/D layout: row = (lane>>4)*4 + reg, col = lane&15  [m89-verified]
    float* yb = out + (size_t)((b*OD + od)*OH + oh) * (OW*CO);
#pragma unroll
    for (int mf = 0; mf < 2; ++mf)
#pragma unroll
        for (int nf = 0; nf < 4; ++nf)
#pragma unroll
            for (int r = 0; r < 4; ++r) {
                int ow = mf*16 + lhi*4 + r;
                int co = nf*16 + l15;
                yb[ow*CO + co] = acc[mf][nf][r];
            }
}

// Per-(b,co) sum and sumsq over spatial. grid = 4*256 blocks.
__global__ __launch_bounds__(256) void stats_kernel(const float* __restrict__ y,
                                                    float* __restrict__ ws) {
    int b   = blockIdx.x >> 8;
    int blk = blockIdx.x & 255;
    int t   = threadIdx.x;
    int co  = t & 63;
    int pq  = t >> 6;
    const float* yb = y + (size_t)b * S_SPATIAL * CO;
    float sum = 0.f, sq = 0.f;
    for (int p = blk*4 + pq; p < S_SPATIAL; p += 1024) {
        float v = yb[(size_t)p*CO + co];
        sum += v;
        sq = fmaf(v, v, sq);
    }
    __shared__ float ssum[256];
    __shared__ float ssq[256];
    ssum[t] = sum; ssq[t] = sq;
    __syncthreads();
    if (t < 64) {
        float s = ssum[t] + ssum[t+64] + ssum[t+128] + ssum[t+192];
        float q = ssq[t]  + ssq[t+64]  + ssq[t+128]  + ssq[t+192];
        atomicAdd(&ws[b*64 + t], s);
        atomicAdd(&ws[256 + b*64 + t], q);
    }
}

// ws[0..255]=sum, ws[256..511]=sumsq  ->  ws[512..767]=scale, ws[768..1023]=shift
__global__ __launch_bounds__(256) void finalize_kernel(float* ws,
                                                       const float* __restrict__ gamma,
                                                       const float* __restrict__ beta) {
    int t = threadIdx.x;       // t = b*64 + co
    int co = t & 63;
    const float invS = 1.0f / (float)S_SPATIAL;
    float sum = ws[t];
    float sq  = ws[256 + t];
    float mu  = sum * invS;
    float var = sq * invS - mu*mu;
    float scale = rsqrtf(var + EPS) * gamma[co];
    ws[512 + t] = scale;
    ws[768 + t] = beta[co] - mu*scale;
}

// In-place normalize + leaky relu, float4 per thread.
__global__ __launch_bounds__(256) void norm_kernel(float* __restrict__ y,
                                                   const float* __restrict__ ws) {
    size_t i = (size_t)blockIdx.x * 256 + threadIdx.x;  // float4 index, total 8388608
    int b = (int)(i >> 21);                              // 2097152 float4 per sample
    const float4* scp = (const float4*)(ws + 512 + b*64);
    const float4* shp = (const float4*)(ws + 768 + b*64);
    float4 sc = scp[i & 15];
    float4 sh = shp[i & 15];
    float4 v = ((const float4*)y)[i];
    float4 r;
    r.x = fmaf(v.x, sc.x, sh.x);
    r.y = fmaf(v.y, sc.y, sh.y);
    r.z = fmaf(v.z, sc.z, sh.z);
    r.w = fmaf(v.w, sc.w, sh.w);
    r.x = r.x >= 0.f ? r.x : ALPHA * r.x;
    r.y = r.y >= 0.f ? r.y : ALPHA * r.y;
    r.z = r.z >= 0.f ? r.z : ALPHA * r.z;
    r.w = r.w >= 0.f ? r.w : ALPHA * r.w;
    ((float4*)y)[i] = r;
}

extern "C" void kernel_launch(void* const* d_in, const int* in_sizes, int n_in,
                              void* d_out, int out_size, void* d_ws, size_t ws_size,
                              hipStream_t stream) {
    const float* x     = (const float*)d_in[0];
    const float* w     = (const float*)d_in[1];
    const float* gamma = (const float*)d_in[2];
    const float* beta  = (const float*)d_in[3];
    float* out = (float*)d_out;
    float* ws  = (float*)d_ws;
    short* wp  = (short*)((char*)d_ws + 4096);   // 884736 B of bf16 B-fragments

    zero_ws_kernel<<<1, 512, 0, stream>>>(ws);
    wprep_kernel<<<B_*27*4, 64, 0, stream>>>(w, wp);
    conv_mfma_kernel<<<B_*OD*(OH/4), 256, 0, stream>>>(x, wp, out);
    stats_kernel<<<B_*256, 256, 0, stream>>>(out, ws);
    finalize_kernel<<<1, 256, 0, stream>>>(ws, gamma, beta);
    norm_kernel<<<32768, 256, 0, stream>>>(out, ws);
}

// Round 3
// 298.488 us; speedup vs baseline: 230.9356x; 1.2208x over previous
//
#include <hip/hip_runtime.h>

#define B_ 4
#define D_ 128
#define H_ 128
#define W_ 32
#define CI 32
#define CO 64
#define OD 64
#define OH 64
#define OW 32
#define S_SPATIAL (OD*OH*OW)   // 131072
#define EPS 1e-5f
#define ALPHA 0.2f

typedef __attribute__((ext_vector_type(8))) short short8;
typedef __attribute__((ext_vector_type(4))) float f32x4;
typedef __attribute__((ext_vector_type(4))) unsigned u32x4;

__device__ inline short f2bf(float f) {
    // RNE float->bf16; compiler fuses pairs into v_cvt_pk_bf16_f32 where possible
    union { float f; unsigned u; } v; v.f = f;
    unsigned r = v.u + 0x7FFFu + ((v.u >> 16) & 1u);
    return (short)(r >> 16);
}

__device__ inline short8 pack8(float4 a, float4 b) {
    short8 r;
    r[0]=f2bf(a.x); r[1]=f2bf(a.y); r[2]=f2bf(a.z); r[3]=f2bf(a.w);
    r[4]=f2bf(b.x); r[5]=f2bf(b.y); r[6]=f2bf(b.z); r[7]=f2bf(b.w);
    return r;
}

__device__ inline short8 mask_frag(short8 v, unsigned m) {
    u32x4 u = __builtin_bit_cast(u32x4, v);
    u[0]&=m; u[1]&=m; u[2]&=m; u[3]&=m;
    return __builtin_bit_cast(short8, u);
}

__global__ __launch_bounds__(512) void zero_ws_kernel(float* ws) {
    ws[threadIdx.x] = 0.f;   // 512 floats: sums + sumsqs
}

// Repack w[b,kd,kh,kw,ci,co] f32 -> bf16 lane-ordered B-fragments.
__global__ __launch_bounds__(64) void wprep_kernel(const float* __restrict__ w,
                                                   short* __restrict__ wp) {
    int blk = blockIdx.x;          // ((b*27+tap)*4+nf)
    int nf  = blk & 3;
    int tb  = blk >> 2;            // b*27+tap
    int l   = threadIdx.x;
    int l15 = l & 15, lhi = l >> 4;
    const float* wsrc = w + (size_t)tb * (CI*CO);   // [ci][co]
    short8 v;
#pragma unroll
    for (int j = 0; j < 8; ++j)
        v[j] = f2bf(wsrc[(lhi*8 + j)*CO + nf*16 + l15]);
    *(short8*)(wp + (size_t)blk*512 + l*8) = v;
}

// Implicit-GEMM conv, M=64/wave. Block = (b, od, oh-octet); wave wv owns oh rows
// ohA=oh0+2wv, ohB=ohA+1. mf: 0=A/ow0-15 1=A/ow16-31 2=B/ow0-15 3=B/ow16-31.
// Fused InstanceNorm stats (sum/sumsq per (b,co)) via shfl+LDS+atomics.
__global__ __launch_bounds__(256) void conv_mfma_kernel(const float* __restrict__ x,
                                                        const short* __restrict__ wp,
                                                        float* __restrict__ out,
                                                        float* __restrict__ ws) {
    const int bid = blockIdx.x;
    const int b   = bid >> 9;
    const int od  = (bid >> 3) & 63;
    const int oh0 = (bid & 7) << 3;
    const int t   = threadIdx.x;
    const int wv  = t >> 6;
    const int l   = t & 63;
    const int l15 = l & 15;
    const int lhi = l >> 4;
    const int ci0 = lhi * 8;
    const int ohA = oh0 + wv*2;    // ohB = ohA+1

    const float* xb  = x + (size_t)b * (D_*H_*W_*CI);
    const short* wpb = wp + (size_t)b * (27*2048);

    // clamped per-lane x offsets (float index) for (half, kw); masks fix the clamp
    int offs[2][3];
#pragma unroll
    for (int h = 0; h < 2; ++h)
#pragma unroll
        for (int kw = 0; kw < 3; ++kw) {
            int iw = h*16 + l15 + kw - 1;
            iw = iw < 0 ? 0 : (iw > 31 ? 31 : iw);
            offs[h][kw] = iw*CI + ci0;
        }
    const unsigned mlo = (l15 == 0)  ? 0u : 0xFFFFFFFFu;  // kw=0, half=0
    const unsigned mhi = (l15 == 15) ? 0u : 0xFFFFFFFFu;  // kw=2, half=1

    f32x4 acc[4][4];
#pragma unroll
    for (int mf = 0; mf < 4; ++mf)
#pragma unroll
        for (int nf = 0; nf < 4; ++nf)
            acc[mf][nf] = (f32x4){0.f, 0.f, 0.f, 0.f};

#pragma unroll
    for (int kd = 0; kd < 3; ++kd) {
        const int id = od*2 + kd;
        if (id < D_) {                                   // block-uniform (od=63 only)
            const float* xsl = xb + (size_t)id * (H_*W_*CI);
#pragma unroll
            for (int kh = 0; kh < 3; ++kh) {
                const int ihA = ohA*2 + kh;              // ihB = ihA+2
                const float* rowA = xsl + (size_t)ihA * (W_*CI);
                const float* rowB = rowA + 2*(W_*CI);
                const short* wrow = wpb + (size_t)((kd*3 + kh)*3) * 2048 + l*8;
                const bool aok = ihA < H_;
                const bool bok = (ihA + 2) < H_;
#pragma unroll
                for (int kw = 0; kw < 3; ++kw) {
                    const short* wpt = wrow + kw*2048;
                    short8 bf0 = *(const short8*)(wpt);
                    short8 bf1 = *(const short8*)(wpt + 512);
                    short8 bf2 = *(const short8*)(wpt + 1024);
                    short8 bf3 = *(const short8*)(wpt + 1536);
                    if (aok) {
                        short8 a0 = pack8(*(const float4*)(rowA + offs[0][kw]),
                                          *(const float4*)(rowA + offs[0][kw] + 4));
                        short8 a1 = pack8(*(const float4*)(rowA + offs[1][kw]),
                                          *(const float4*)(rowA + offs[1][kw] + 4));
                        if (kw == 0) a0 = mask_frag(a0, mlo);
                        if (kw == 2) a1 = mask_frag(a1, mhi);
                        acc[0][0] = __builtin_amdgcn_mfma_f32_16x16x32_bf16(a0, bf0, acc[0][0], 0,0,0);
                        acc[0][1] = __builtin_amdgcn_mfma_f32_16x16x32_bf16(a0, bf1, acc[0][1], 0,0,0);
                        acc[0][2] = __builtin_amdgcn_mfma_f32_16x16x32_bf16(a0, bf2, acc[0][2], 0,0,0);
                        acc[0][3] = __builtin_amdgcn_mfma_f32_16x16x32_bf16(a0, bf3, acc[0][3], 0,0,0);
                        acc[1][0] = __builtin_amdgcn_mfma_f32_16x16x32_bf16(a1, bf0, acc[1][0], 0,0,0);
                        acc[1][1] = __builtin_amdgcn_mfma_f32_16x16x32_bf16(a1, bf1, acc[1][1], 0,0,0);
                        acc[1][2] = __builtin_amdgcn_mfma_f32_16x16x32_bf16(a1, bf2, acc[1][2], 0,0,0);
                        acc[1][3] = __builtin_amdgcn_mfma_f32_16x16x32_bf16(a1, bf3, acc[1][3], 0,0,0);
                    }
                    if (bok) {
                        short8 c0 = pack8(*(const float4*)(rowB + offs[0][kw]),
                                          *(const float4*)(rowB + offs[0][kw] + 4));
                        short8 c1 = pack8(*(const float4*)(rowB + offs[1][kw]),
                                          *(const float4*)(rowB + offs[1][kw] + 4));
                        if (kw == 0) c0 = mask_frag(c0, mlo);
                        if (kw == 2) c1 = mask_frag(c1, mhi);
                        acc[2][0] = __builtin_amdgcn_mfma_f32_16x16x32_bf16(c0, bf0, acc[2][0], 0,0,0);
                        acc[2][1] = __builtin_amdgcn_mfma_f32_16x16x32_bf16(c0, bf1, acc[2][1], 0,0,0);
                        acc[2][2] = __builtin_amdgcn_mfma_f32_16x16x32_bf16(c0, bf2, acc[2][2], 0,0,0);
                        acc[2][3] = __builtin_amdgcn_mfma_f32_16x16x32_bf16(c0, bf3, acc[2][3], 0,0,0);
                        acc[3][0] = __builtin_amdgcn_mfma_f32_16x16x32_bf16(c1, bf0, acc[3][0], 0,0,0);
                        acc[3][1] = __builtin_amdgcn_mfma_f32_16x16x32_bf16(c1, bf1, acc[3][1], 0,0,0);
                        acc[3][2] = __builtin_amdgcn_mfma_f32_16x16x32_bf16(c1, bf2, acc[3][2], 0,0,0);
                        acc[3][3] = __builtin_amdgcn_mfma_f32_16x16x32_bf16(c1, bf3, acc[3][3], 0,0,0);
                    }
                }
            }
        }
    }

    // C-write. C/D: row = lhi*4 + r, col = l15 [m89]
    float* ybA = out + (size_t)((b*OD + od)*OH + ohA) * (OW*CO);
#pragma unroll
    for (int mf = 0; mf < 4; ++mf) {
        float* yb = ybA + (size_t)(mf >> 1) * (OW*CO);
#pragma unroll
        for (int nf = 0; nf < 4; ++nf)
#pragma unroll
            for (int r = 0; r < 4; ++r) {
                int ow = (mf & 1)*16 + lhi*4 + r;
                int co = nf*16 + l15;
                yb[ow*CO + co] = acc[mf][nf][r];
            }
    }

    // Fused InstanceNorm stats: per-lane col partials -> lane group -> LDS -> atomics
    float csum[4], csq[4];
#pragma unroll
    for (int nf = 0; nf < 4; ++nf) {
        float s = 0.f, q = 0.f;
#pragma unroll
        for (int mf = 0; mf < 4; ++mf)
#pragma unroll
            for (int r = 0; r < 4; ++r) {
                float v = acc[mf][nf][r];
                s += v;
                q = fmaf(v, v, q);
            }
        s += __shfl_xor(s, 16, 64); s += __shfl_xor(s, 32, 64);
        q += __shfl_xor(q, 16, 64); q += __shfl_xor(q, 32, 64);
        csum[nf] = s; csq[nf] = q;
    }
    __shared__ float lsum[4][64];
    __shared__ float lsq[4][64];
    if (lhi == 0) {
#pragma unroll
        for (int nf = 0; nf < 4; ++nf) {
            lsum[wv][nf*16 + l15] = csum[nf];
            lsq[wv][nf*16 + l15]  = csq[nf];
        }
    }
    __syncthreads();
    if (t < 64) {
        float s = lsum[0][t] + lsum[1][t] + lsum[2][t] + lsum[3][t];
        float q = lsq[0][t]  + lsq[1][t]  + lsq[2][t]  + lsq[3][t];
        atomicAdd(&ws[b*64 + t], s);
        atomicAdd(&ws[256 + b*64 + t], q);
    }
}

// ws[0..255]=sum, ws[256..511]=sumsq  ->  ws[512..767]=scale, ws[768..1023]=shift
__global__ __launch_bounds__(256) void finalize_kernel(float* ws,
                                                       const float* __restrict__ gamma,
                                                       const float* __restrict__ beta) {
    int t = threadIdx.x;       // t = b*64 + co
    int co = t & 63;
    const float invS = 1.0f / (float)S_SPATIAL;
    float sum = ws[t];
    float sq  = ws[256 + t];
    float mu  = sum * invS;
    float var = sq * invS - mu*mu;
    float scale = rsqrtf(var + EPS) * gamma[co];
    ws[512 + t] = scale;
    ws[768 + t] = beta[co] - mu*scale;
}

// In-place normalize + leaky relu, float4 per thread.
__global__ __launch_bounds__(256) void norm_kernel(float* __restrict__ y,
                                                   const float* __restrict__ ws) {
    size_t i = (size_t)blockIdx.x * 256 + threadIdx.x;  // float4 index, total 8388608
    int b = (int)(i >> 21);                              // 2097152 float4 per sample
    const float4* scp = (const float4*)(ws + 512 + b*64);
    const float4* shp = (const float4*)(ws + 768 + b*64);
    float4 sc = scp[i & 15];
    float4 sh = shp[i & 15];
    float4 v = ((const float4*)y)[i];
    float4 r;
    r.x = fmaf(v.x, sc.x, sh.x);
    r.y = fmaf(v.y, sc.y, sh.y);
    r.z = fmaf(v.z, sc.z, sh.z);
    r.w = fmaf(v.w, sc.w, sh.w);
    r.x = r.x >= 0.f ? r.x : ALPHA * r.x;
    r.y = r.y >= 0.f ? r.y : ALPHA * r.y;
    r.z = r.z >= 0.f ? r.z : ALPHA * r.z;
    r.w = r.w >= 0.f ? r.w : ALPHA * r.w;
    ((float4*)y)[i] = r;
}

extern "C" void kernel_launch(void* const* d_in, const int* in_sizes, int n_in,
                              void* d_out, int out_size, void* d_ws, size_t ws_size,
                              hipStream_t stream) {
    const float* x     = (const float*)d_in[0];
    const float* w     = (const float*)d_in[1];
    const float* gamma = (const float*)d_in[2];
    const float* beta  = (const float*)d_in[3];
    float* out = (float*)d_out;
    float* ws  = (float*)d_ws;
    short* wp  = (short*)((char*)d_ws + 4096);   // bf16 B-fragments (884736 B)

    zero_ws_kernel<<<1, 512, 0, stream>>>(ws);
    wprep_kernel<<<B_*27*4, 64, 0, stream>>>(w, wp);
    conv_mfma_kernel<<<B_*OD*(OH/8), 256, 0, stream>>>(x, wp, out, ws);
    finalize_kernel<<<1, 256, 0, stream>>>(ws, gamma, beta);
    norm_kernel<<<32768, 256, 0, stream>>>(out, ws);
}

// Round 4
// 210.922 us; speedup vs baseline: 326.8100x; 1.4152x over previous
//
#include <hip/hip_runtime.h>

#define B_ 4
#define D_ 128
#define H_ 128
#define W_ 32
#define CI 32
#define CO 64
#define OD 64
#define OH 64
#define OW 32
#define S_SPATIAL (OD*OH*OW)   // 131072
#define EPS 1e-5f
#define ALPHA 0.2f

#define XR 17                   // x-tile rows per kd slice (ih span of an oh-octet)
#define XC 34                   // x-tile cols incl. W halo (iw=-1..32 zero-padded)

typedef __attribute__((ext_vector_type(8))) short short8;
typedef __attribute__((ext_vector_type(4))) float f32x4;

__device__ inline short f2bf(float f) {
    // RNE float->bf16
    union { float f; unsigned u; } v; v.f = f;
    unsigned r = v.u + 0x7FFFu + ((v.u >> 16) & 1u);
    return (short)(r >> 16);
}

__device__ inline short8 pack8(float4 a, float4 b) {
    short8 r;
    r[0]=f2bf(a.x); r[1]=f2bf(a.y); r[2]=f2bf(a.z); r[3]=f2bf(a.w);
    r[4]=f2bf(b.x); r[5]=f2bf(b.y); r[6]=f2bf(b.z); r[7]=f2bf(b.w);
    return r;
}

__global__ __launch_bounds__(512) void zero_ws_kernel(float* ws) {
    ws[threadIdx.x] = 0.f;   // 512 floats: sums + sumsqs
}

// Repack w[b,kd,kh,kw,ci,co] f32 -> bf16 lane-ordered B-fragments.
__global__ __launch_bounds__(64) void wprep_kernel(const float* __restrict__ w,
                                                   short* __restrict__ wp) {
    int blk = blockIdx.x;          // ((b*27+tap)*4+nf)
    int nf  = blk & 3;
    int tb  = blk >> 2;            // b*27+tap
    int l   = threadIdx.x;
    int l15 = l & 15, lhi = l >> 4;
    const float* wsrc = w + (size_t)tb * (CI*CO);   // [ci][co]
    short8 v;
#pragma unroll
    for (int j = 0; j < 8; ++j)
        v[j] = f2bf(wsrc[(lhi*8 + j)*CO + nf*16 + l15]);
    *(short8*)(wp + (size_t)blk*512 + l*8) = v;
}

// Implicit-GEMM conv with LDS-staged bf16 x tile, kd-streamed.
// Block = (b, od, oh-octet); wave wv owns oh rows 2wv, 2wv+1.
// mf: 0={rowA,ow0-15} 1={rowA,ow16-31} 2={rowB,ow0-15} 3={rowB,ow16-31}.
// Fused InstanceNorm stats via shfl + LDS + one atomic pair per block.
__global__ __launch_bounds__(256) void conv_mfma_kernel(const float* __restrict__ x,
                                                        const short* __restrict__ wp,
                                                        float* __restrict__ out,
                                                        float* __restrict__ ws) {
    const int bid = blockIdx.x;
    const int b   = bid >> 9;
    const int od  = (bid >> 3) & 63;
    const int oh0 = (bid & 7) << 3;
    const int t   = threadIdx.x;
    const int wv  = t >> 6;
    const int l   = t & 63;
    const int l15 = l & 15;
    const int lhi = l >> 4;

    const float* xb  = x + (size_t)b * (D_*H_*W_*CI);
    const short* wpb = wp + (size_t)b * (27*2048);

    // xlds[g][r][c] of 8-bf16 units: conflict-free lane-contiguous ds_read_b128
    __shared__ short xlds[4*XR*XC*8];   // 36992 B
    __shared__ float lsum[4][64];
    __shared__ float lsq[4][64];

    f32x4 acc[4][4];
#pragma unroll
    for (int mf = 0; mf < 4; ++mf)
#pragma unroll
        for (int nf = 0; nf < 4; ++nf)
            acc[mf][nf] = (f32x4){0.f, 0.f, 0.f, 0.f};

    for (int kd = 0; kd < 3; ++kd) {
        const int id = od*2 + kd;
        if (id >= D_) break;                        // block-uniform (od=63 only)
        const float* xsl = xb + (size_t)id * (H_*W_*CI);

        __syncthreads();                            // previous slice's reads done
        for (int u = t; u < 4*XR*XC; u += 256) {
            int c  = u % XC;
            int rc = u / XC;
            int r  = rc % XR;
            int g  = rc / XR;
            int ih = oh0*2 + r;
            int iw = c - 1;
            short8 v = (short8){0,0,0,0,0,0,0,0};
            if (ih < H_ && (unsigned)iw < (unsigned)W_) {
                const float* p = xsl + (size_t)ih*(W_*CI) + iw*CI + g*8;
                v = pack8(*(const float4*)p, *(const float4*)(p + 4));
            }
            *(short8*)(xlds + (size_t)u*8) = v;
        }
        __syncthreads();

        const short* wkd = wpb + (size_t)kd*(9*2048) + l*8;
#pragma unroll
        for (int kh = 0; kh < 3; ++kh) {
#pragma unroll
            for (int kw = 0; kw < 3; ++kw) {
                const short* wpt = wkd + (kh*3 + kw)*2048;
                short8 bf0 = *(const short8*)(wpt);
                short8 bf1 = *(const short8*)(wpt + 512);
                short8 bf2 = *(const short8*)(wpt + 1024);
                short8 bf3 = *(const short8*)(wpt + 1536);
#pragma unroll
                for (int mf = 0; mf < 4; ++mf) {
                    int oh_l = 2*wv + (mf >> 1);
                    int r    = 2*oh_l + kh;
                    int c    = (mf & 1)*16 + l15 + kw;
                    short8 a = *(const short8*)(xlds + (((lhi*XR + r)*XC + c) * 8));
                    acc[mf][0] = __builtin_amdgcn_mfma_f32_16x16x32_bf16(a, bf0, acc[mf][0], 0,0,0);
                    acc[mf][1] = __builtin_amdgcn_mfma_f32_16x16x32_bf16(a, bf1, acc[mf][1], 0,0,0);
                    acc[mf][2] = __builtin_amdgcn_mfma_f32_16x16x32_bf16(a, bf2, acc[mf][2], 0,0,0);
                    acc[mf][3] = __builtin_amdgcn_mfma_f32_16x16x32_bf16(a, bf3, acc[mf][3], 0,0,0);
                }
            }
        }
    }

    // C-write. C/D: row = lhi*4 + r, col = l15 [m89]
    const int ohA = oh0 + wv*2;
    float* ybA = out + (size_t)((b*OD + od)*OH + ohA) * (OW*CO);
#pragma unroll
    for (int mf = 0; mf < 4; ++mf) {
        float* yb = ybA + (size_t)(mf >> 1) * (OW*CO);
#pragma unroll
        for (int nf = 0; nf < 4; ++nf)
#pragma unroll
            for (int r = 0; r < 4; ++r) {
                int ow = (mf & 1)*16 + lhi*4 + r;
                int co = nf*16 + l15;
                yb[ow*CO + co] = acc[mf][nf][r];
            }
    }

    // Fused InstanceNorm stats
    float csum[4], csq[4];
#pragma unroll
    for (int nf = 0; nf < 4; ++nf) {
        float s = 0.f, q = 0.f;
#pragma unroll
        for (int mf = 0; mf < 4; ++mf)
#pragma unroll
            for (int r = 0; r < 4; ++r) {
                float v = acc[mf][nf][r];
                s += v;
                q = fmaf(v, v, q);
            }
        s += __shfl_xor(s, 16, 64); s += __shfl_xor(s, 32, 64);
        q += __shfl_xor(q, 16, 64); q += __shfl_xor(q, 32, 64);
        csum[nf] = s; csq[nf] = q;
    }
    if (lhi == 0) {
#pragma unroll
        for (int nf = 0; nf < 4; ++nf) {
            lsum[wv][nf*16 + l15] = csum[nf];
            lsq[wv][nf*16 + l15]  = csq[nf];
        }
    }
    __syncthreads();
    if (t < 64) {
        float s = lsum[0][t] + lsum[1][t] + lsum[2][t] + lsum[3][t];
        float q = lsq[0][t]  + lsq[1][t]  + lsq[2][t]  + lsq[3][t];
        atomicAdd(&ws[b*64 + t], s);
        atomicAdd(&ws[256 + b*64 + t], q);
    }
}

// ws[0..255]=sum, ws[256..511]=sumsq  ->  ws[512..767]=scale, ws[768..1023]=shift
__global__ __launch_bounds__(256) void finalize_kernel(float* ws,
                                                       const float* __restrict__ gamma,
                                                       const float* __restrict__ beta) {
    int t = threadIdx.x;       // t = b*64 + co
    int co = t & 63;
    const float invS = 1.0f / (float)S_SPATIAL;
    float sum = ws[t];
    float sq  = ws[256 + t];
    float mu  = sum * invS;
    float var = sq * invS - mu*mu;
    float scale = rsqrtf(var + EPS) * gamma[co];
    ws[512 + t] = scale;
    ws[768 + t] = beta[co] - mu*scale;
}

// In-place normalize + leaky relu, float4 per thread.
__global__ __launch_bounds__(256) void norm_kernel(float* __restrict__ y,
                                                   const float* __restrict__ ws) {
    size_t i = (size_t)blockIdx.x * 256 + threadIdx.x;  // float4 index, total 8388608
    int b = (int)(i >> 21);                              // 2097152 float4 per sample
    const float4* scp = (const float4*)(ws + 512 + b*64);
    const float4* shp = (const float4*)(ws + 768 + b*64);
    float4 sc = scp[i & 15];
    float4 sh = shp[i & 15];
    float4 v = ((const float4*)y)[i];
    float4 r;
    r.x = fmaf(v.x, sc.x, sh.x);
    r.y = fmaf(v.y, sc.y, sh.y);
    r.z = fmaf(v.z, sc.z, sh.z);
    r.w = fmaf(v.w, sc.w, sh.w);
    r.x = r.x >= 0.f ? r.x : ALPHA * r.x;
    r.y = r.y >= 0.f ? r.y : ALPHA * r.y;
    r.z = r.z >= 0.f ? r.z : ALPHA * r.z;
    r.w = r.w >= 0.f ? r.w : ALPHA * r.w;
    ((float4*)y)[i] = r;
}

extern "C" void kernel_launch(void* const* d_in, const int* in_sizes, int n_in,
                              void* d_out, int out_size, void* d_ws, size_t ws_size,
                              hipStream_t stream) {
    const float* x     = (const float*)d_in[0];
    const float* w     = (const float*)d_in[1];
    const float* gamma = (const float*)d_in[2];
    const float* beta  = (const float*)d_in[3];
    float* out = (float*)d_out;
    float* ws  = (float*)d_ws;
    short* wp  = (short*)((char*)d_ws + 4096);   // bf16 B-fragments (442368 B)

    zero_ws_kernel<<<1, 512, 0, stream>>>(ws);
    wprep_kernel<<<B_*27*4, 64, 0, stream>>>(w, wp);
    conv_mfma_kernel<<<B_*OD*(OH/8), 256, 0, stream>>>(x, wp, out, ws);
    finalize_kernel<<<1, 256, 0, stream>>>(ws, gamma, beta);
    norm_kernel<<<32768, 256, 0, stream>>>(out, ws);
}